// Round 11
// baseline (648.239 us; speedup 1.0000x reference)
//
#include <hip/hip_runtime.h>
#include <math.h>

#define KC 16
#define DF 256

// ws layout
#define WS_POOLED 0          // [16*256] S^T F accumulator (floats)
#define WS_CS     4096       // [16] cluster sizes
#define WS_M      4112       // [16] m_k = sum_e val*S[row][k]
#define WS_TR     4128       // trace accumulator
#define WS_ESUM   4129       // sum of edge_val (= 2*n_edges)
#define WS_DONE   4130       // edge_pool completion counter (uint bits)
#define WS_TOTAL  4131
#define SHDW_OFF_BYTES 16640 // fp8 S shadow, 16 B/node, 16B-aligned

// NOTE: no __has_builtin / arch preprocessor gating (host/device pass divergence
// caused the round-0 core dump). gfx950 always has the fp8 cvt builtins.
// RULE (r10): W addresses must stay wave-uniform (scalar loads). Lane-varying
// W indexing turns the 1024-MAC/thread loop into 1024 vector gathers (242 us).

typedef float floatx2 __attribute__((ext_vector_type(2)));

// 16 fp8 (OCP e4m3fn) -> 16 f32 via 8 packed HW converts.
__device__ __forceinline__ void cvt16_fp8(uint4 u, float* f) {
  floatx2 p;
  p = __builtin_amdgcn_cvt_pk_f32_fp8(u.x, false); f[0] = p[0];  f[1] = p[1];
  p = __builtin_amdgcn_cvt_pk_f32_fp8(u.x, true);  f[2] = p[0];  f[3] = p[1];
  p = __builtin_amdgcn_cvt_pk_f32_fp8(u.y, false); f[4] = p[0];  f[5] = p[1];
  p = __builtin_amdgcn_cvt_pk_f32_fp8(u.y, true);  f[6] = p[0];  f[7] = p[1];
  p = __builtin_amdgcn_cvt_pk_f32_fp8(u.z, false); f[8] = p[0];  f[9] = p[1];
  p = __builtin_amdgcn_cvt_pk_f32_fp8(u.z, true);  f[10] = p[0]; f[11] = p[1];
  p = __builtin_amdgcn_cvt_pk_f32_fp8(u.w, false); f[12] = p[0]; f[13] = p[1];
  p = __builtin_amdgcn_cvt_pk_f32_fp8(u.w, true);  f[14] = p[0]; f[15] = p[1];
}

__device__ __forceinline__ void acc_edge1(uint4 A, uint4 B, float vq,
                                          float* m, float& tr, float& es) {
  float a[16], bb[16];
  cvt16_fp8(A, a); cvt16_fp8(B, bb);
  float d = 0.f;
  #pragma unroll
  for (int k = 0; k < 16; ++k) d += a[k] * bb[k];
  tr += vq * d; es += vq;
  #pragma unroll
  for (int k = 0; k < 16; ++k) m[k] += vq * a[k];
}

// ---------------------------------------------------------------------------
// assign: VERBATIM r4/r7 version (measured 70 us at 290-total): thread=node,
// W wave-uniform (scalar loads), F staged transposed in double-buffered LDS.
// ---------------------------------------------------------------------------
__global__ void __launch_bounds__(256, 2) assign_kernel(
    const float* __restrict__ F, const float* __restrict__ W,
    const float* __restrict__ b, float* __restrict__ S,
    unsigned* __restrict__ Sh, float* __restrict__ ws, int n) {
  __shared__ float Ft[2][32 * 257];
  __shared__ float cs_l[KC];
  const int t = threadIdx.x;
  if (t < KC) cs_l[t] = 0.0f;
  const int nb = blockIdx.x << 8;
  const int node = nb + t;
  const bool valid = node < n;
  const bool interior = (nb + 256 <= n);

  const int nl = t >> 3;          // staged node within tile (per 'it' offset)
  const int jc = t & 7;           // float4 slot within 32-feature row

  float4 pref[8];
  auto load_chunk = [&](int s) {
    #pragma unroll
    for (int it = 0; it < 8; ++it) {
      const int nn = nl + (it << 5);
      if (interior || nb + nn < n)
        pref[it] = *(const float4*)&F[(size_t)(nb + nn) * DF + (s << 5) + (jc << 2)];
      else
        pref[it] = make_float4(0.f, 0.f, 0.f, 0.f);
    }
  };

  float acc[KC];
  #pragma unroll
  for (int k = 0; k < KC; ++k) acc[k] = 0.f;

  load_chunk(0);
  for (int s = 0; s < 8; ++s) {
    float* __restrict__ B = Ft[s & 1];
    // Writes to buffer (s&1) are safe without a leading barrier: the last
    // reads of this buffer (compute s-2) precede the barrier of iter s-1.
    #pragma unroll
    for (int it = 0; it < 8; ++it) {
      const int nn = nl + (it << 5);
      const int d0 = jc << 2;
      B[(d0 + 0) * 257 + nn] = pref[it].x;
      B[(d0 + 1) * 257 + nn] = pref[it].y;
      B[(d0 + 2) * 257 + nn] = pref[it].z;
      B[(d0 + 3) * 257 + nn] = pref[it].w;
    }
    __syncthreads();
    if (s < 7) load_chunk(s + 1);  // in flight during compute below
    #pragma unroll
    for (int j = 0; j < 8; ++j) {
      const float fv0 = B[(4 * j + 0) * 257 + t];
      const float fv1 = B[(4 * j + 1) * 257 + t];
      const float fv2 = B[(4 * j + 2) * 257 + t];
      const float fv3 = B[(4 * j + 3) * 257 + t];
      const float* __restrict__ Wg = &W[(size_t)((s << 5) + (j << 2)) * KC];
      #pragma unroll
      for (int k = 0; k < KC; ++k)
        acc[k] += fv0 * Wg[k] + fv1 * Wg[KC + k]
                + fv2 * Wg[2 * KC + k] + fv3 * Wg[3 * KC + k];
    }
  }

  // thread-local softmax
  float mx = -1e30f;
  #pragma unroll
  for (int k = 0; k < KC; ++k) { acc[k] += b[k]; mx = fmaxf(mx, acc[k]); }
  float sum = 0.f;
  #pragma unroll
  for (int k = 0; k < KC; ++k) { acc[k] = __expf(acc[k] - mx); sum += acc[k]; }
  const float inv = 1.0f / sum;
  #pragma unroll
  for (int k = 0; k < KC; ++k) acc[k] *= inv;
  if (!valid) {
    #pragma unroll
    for (int k = 0; k < KC; ++k) acc[k] = 0.f;
  }
  if (valid) {
    float4* __restrict__ So = (float4*)&S[(size_t)node * KC];
    So[0] = make_float4(acc[0],  acc[1],  acc[2],  acc[3]);
    So[1] = make_float4(acc[4],  acc[5],  acc[6],  acc[7]);
    So[2] = make_float4(acc[8],  acc[9],  acc[10], acc[11]);
    So[3] = make_float4(acc[12], acc[13], acc[14], acc[15]);
    if (Sh) {
      unsigned w0, w1, w2, w3;
      w0 = __builtin_amdgcn_cvt_pk_fp8_f32(acc[0],  acc[1],  0,  false);
      w0 = __builtin_amdgcn_cvt_pk_fp8_f32(acc[2],  acc[3],  w0, true);
      w1 = __builtin_amdgcn_cvt_pk_fp8_f32(acc[4],  acc[5],  0,  false);
      w1 = __builtin_amdgcn_cvt_pk_fp8_f32(acc[6],  acc[7],  w1, true);
      w2 = __builtin_amdgcn_cvt_pk_fp8_f32(acc[8],  acc[9],  0,  false);
      w2 = __builtin_amdgcn_cvt_pk_fp8_f32(acc[10], acc[11], w2, true);
      w3 = __builtin_amdgcn_cvt_pk_fp8_f32(acc[12], acc[13], 0,  false);
      w3 = __builtin_amdgcn_cvt_pk_fp8_f32(acc[14], acc[15], w3, true);
      *(uint4*)&Sh[(size_t)node * 4] = make_uint4(w0, w1, w2, w3);
    }
  }
  // cluster sizes
  #pragma unroll
  for (int off = 1; off < 64; off <<= 1) {
    #pragma unroll
    for (int k = 0; k < KC; ++k) acc[k] += __shfl_xor(acc[k], off);
  }
  if ((t & 63) == 0) {
    #pragma unroll
    for (int k = 0; k < KC; ++k) atomicAdd(&cs_l[k], acc[k]);
  }
  __syncthreads();
  if (t < KC) atomicAdd(&ws[WS_CS + t], cs_l[t]);
}

// ---------------------------------------------------------------------------
// Edge body (fp8): contiguous 2048-edge chunk per block 'idx', all 16
// S-gathers into named registers before compute.
// ---------------------------------------------------------------------------
__device__ __forceinline__ void edge_body_fp8(
    const int* __restrict__ erow, const int* __restrict__ ecol,
    const float* __restrict__ evl, const uint4* __restrict__ S8,
    float* __restrict__ ws, int ne, int idx, float* __restrict__ red) {
  const int t = threadIdx.x;
  if (t < KC + 2) red[t] = 0.0f;
  __syncthreads();

  float m[KC];
  #pragma unroll
  for (int i = 0; i < KC; ++i) m[i] = 0.f;
  float tr = 0.f, es = 0.f;

  const int cbase = idx << 11;            // 2048 edges per block
  const int base = cbase + t;
  int r[8], c[8];
  float v[8];
  if (cbase + 2048 <= ne) {               // interior fast path
    #pragma unroll
    for (int i = 0; i < 8; ++i) {
      const int e = base + (i << 8);
      r[i] = erow[e]; c[i] = ecol[e]; v[i] = evl[e];
    }
  } else {
    #pragma unroll
    for (int i = 0; i < 8; ++i) {
      const int e = base + (i << 8);
      const bool ok = e < ne;
      r[i] = ok ? erow[e] : 0;
      c[i] = ok ? ecol[e] : 0;
      v[i] = ok ? evl[e] : 0.f;
    }
  }

  const uint4 A0 = S8[r[0]], B0 = S8[c[0]], A1 = S8[r[1]], B1 = S8[c[1]],
              A2 = S8[r[2]], B2 = S8[c[2]], A3 = S8[r[3]], B3 = S8[c[3]],
              A4 = S8[r[4]], B4 = S8[c[4]], A5 = S8[r[5]], B5 = S8[c[5]],
              A6 = S8[r[6]], B6 = S8[c[6]], A7 = S8[r[7]], B7 = S8[c[7]];
  acc_edge1(A0, B0, v[0], m, tr, es);
  acc_edge1(A1, B1, v[1], m, tr, es);
  acc_edge1(A2, B2, v[2], m, tr, es);
  acc_edge1(A3, B3, v[3], m, tr, es);
  acc_edge1(A4, B4, v[4], m, tr, es);
  acc_edge1(A5, B5, v[5], m, tr, es);
  acc_edge1(A6, B6, v[6], m, tr, es);
  acc_edge1(A7, B7, v[7], m, tr, es);

  #pragma unroll
  for (int off = 1; off < 64; off <<= 1) {
    tr += __shfl_xor(tr, off);
    es += __shfl_xor(es, off);
    #pragma unroll
    for (int i = 0; i < KC; ++i) m[i] += __shfl_xor(m[i], off);
  }
  if ((t & 63) == 0) {
    atomicAdd(&red[KC], tr);
    atomicAdd(&red[KC + 1], es);
    #pragma unroll
    for (int i = 0; i < KC; ++i) atomicAdd(&red[i], m[i]);
  }
  __syncthreads();
  if (t < KC)            atomicAdd(&ws[WS_M + t], red[t]);
  else if (t == KC)      atomicAdd(&ws[WS_TR], red[KC]);
  else if (t == KC + 1)  atomicAdd(&ws[WS_ESUM], red[KC + 1]);
}

// ---------------------------------------------------------------------------
// Pool body: r4 pool_kernel with explicit (idx, pg).
// ---------------------------------------------------------------------------
__device__ __forceinline__ void pool_body(
    const float* __restrict__ F, const float* __restrict__ S,
    float* __restrict__ ws, int n, int idx, int pg) {
  const int t = threadIdx.x;
  float acc[KC];
  #pragma unroll
  for (int i = 0; i < KC; ++i) acc[i] = 0.f;

  const int nch = n >> 5;
  for (int ch = idx; ch < nch; ch += pg) {
    const int base = ch << 5;
    float fl[32];
    #pragma unroll
    for (int i = 0; i < 32; ++i)
      fl[i] = F[(size_t)(base + i) * DF + t];
    #pragma unroll
    for (int i = 0; i < 32; ++i) {
      const float4* __restrict__ Sr = (const float4*)(S + (size_t)(base + i) * KC);
      const float4 s0 = Sr[0], s1 = Sr[1], s2 = Sr[2], s3 = Sr[3];
      const float f = fl[i];
      acc[0]+=f*s0.x;  acc[1]+=f*s0.y;  acc[2]+=f*s0.z;  acc[3]+=f*s0.w;
      acc[4]+=f*s1.x;  acc[5]+=f*s1.y;  acc[6]+=f*s1.z;  acc[7]+=f*s1.w;
      acc[8]+=f*s2.x;  acc[9]+=f*s2.y;  acc[10]+=f*s2.z; acc[11]+=f*s2.w;
      acc[12]+=f*s3.x; acc[13]+=f*s3.y; acc[14]+=f*s3.z; acc[15]+=f*s3.w;
    }
  }
  if (idx == 0) {                        // tail (n % 32)
    for (int i2 = nch << 5; i2 < n; ++i2) {
      const float f = F[(size_t)i2 * DF + t];
      const float* __restrict__ Sr = S + (size_t)i2 * KC;
      #pragma unroll
      for (int kk = 0; kk < KC; ++kk) acc[kk] += f * Sr[kk];
    }
  }
  const int rot = idx & 15;
  #pragma unroll
  for (int kk = 0; kk < KC; ++kk) {
    const int kidx = (kk + rot) & 15;
    atomicAdd(&ws[WS_POOLED + kidx * DF + t], acc[kidx]);
  }
}

// ---------------------------------------------------------------------------
// Finalize body: run by the LAST edge_pool block. All ws reads via
// atomicAdd(p, 0) -> L2-coherent (no stale-L1 risk).
// ---------------------------------------------------------------------------
__device__ void finalize_body(float* __restrict__ ws, float* __restrict__ out,
                              int n) {
  __shared__ float s_cs[KC], s_sc[4];
  const int t = threadIdx.x;
  if (t < KC) s_cs[t] = atomicAdd(&ws[WS_CS + t], 0.0f);
  __syncthreads();
  const float alpha = 1.6732632423543772f;
  const float scale = 1.0507009873554805f;
  for (int idx = t; idx < KC * DF; idx += 256) {
    const int k = idx >> 8;
    const float x = atomicAdd(&ws[WS_POOLED + idx], 0.0f) / s_cs[k];
    const float r = x > 0.f ? x : alpha * expm1f(x);
    out[idx] = scale * r;
  }
  if (t == 0) {
    const float esum = atomicAdd(&ws[WS_ESUM], 0.0f);   // = 2 * n_edges
    const float tr = atomicAdd(&ws[WS_TR], 0.0f);
    float sm2 = 0.f, sc2 = 0.f;
    for (int i = 0; i < KC; ++i) {
      const float mi = atomicAdd(&ws[WS_M + i], 0.0f);
      sm2 += mi * mi;
      const float ci = s_cs[i];
      sc2 += ci * ci;
    }
    const float spectral = -(tr - sm2 / esum) / esum;
    const float collapse = 0.1f * (sqrtf(sc2) / (float)n * 4.0f - 1.0f);
    const size_t off = (size_t)(KC * DF) + (size_t)n * KC;
    out[off] = spectral;
    out[off + 1] = collapse;
    (void)s_sc;
  }
}

// ---------------------------------------------------------------------------
// Merged edge+pool dispatch (r7: 95 us @ 1.2 TB/s) + last-block finalize
// (saves one dispatch boundary; r7/r10 showed ~115 us of inter-dispatch gaps).
// ---------------------------------------------------------------------------
__global__ void __launch_bounds__(256) edge_pool_kernel(
    const int* __restrict__ erow, const int* __restrict__ ecol,
    const float* __restrict__ evl, const uint4* __restrict__ S8,
    const float* __restrict__ F, const float* __restrict__ S,
    float* __restrict__ ws, float* __restrict__ out,
    int ne, int n, int pg, int eg) {
  __shared__ float red[KC + 2];
  __shared__ int lastFlag;
  const int bid = blockIdx.x;
  const int mn = pg < eg ? pg : eg;
  const int nInter = 2 * mn;
  int role, idx;
  if (bid < nInter) { role = bid & 1; idx = bid >> 1; }
  else {
    const int rem = bid - nInter;
    role = (pg > eg) ? 0 : 1;
    idx = mn + rem;
  }
  if (role == 0) pool_body(F, S, ws, n, idx, pg);
  else           edge_body_fp8(erow, ecol, evl, S8, ws, ne, idx, red);

  // last-block finalize: fence own writes, sync, bump device counter.
  __threadfence();
  __syncthreads();
  if (threadIdx.x == 0) {
    unsigned old = atomicAdd((unsigned*)ws + WS_DONE, 1u);
    lastFlag = (old == (unsigned)(gridDim.x - 1)) ? 1 : 0;
  }
  __syncthreads();
  if (lastFlag) {
    __threadfence();
    finalize_body(ws, out, n);
  }
}

// fp32 fallback (ws too small for the fp8 shadow) — runtime choice.
__global__ void __launch_bounds__(256) edge_kernel_f32(
    const int* __restrict__ erow, const int* __restrict__ ecol,
    const float* __restrict__ evl, const float* __restrict__ S,
    float* __restrict__ ws, int ne) {
  __shared__ float red[KC + 2];
  const int t = threadIdx.x;
  if (t < KC + 2) red[t] = 0.0f;
  __syncthreads();
  float m[KC];
  #pragma unroll
  for (int i = 0; i < KC; ++i) m[i] = 0.f;
  float tr = 0.f, es = 0.f;
  const int stride = gridDim.x * blockDim.x;
  for (int e = blockIdx.x * blockDim.x + t; e < ne; e += stride) {
    const int r = erow[e];
    const int c = ecol[e];
    const float v = evl[e];
    const float4* __restrict__ Sr = (const float4*)(S + (size_t)r * KC);
    const float4* __restrict__ Sc = (const float4*)(S + (size_t)c * KC);
    const float4 a0 = Sr[0], a1 = Sr[1], a2 = Sr[2], a3 = Sr[3];
    const float4 b0 = Sc[0], b1 = Sc[1], b2 = Sc[2], b3 = Sc[3];
    float d = a0.x*b0.x + a0.y*b0.y + a0.z*b0.z + a0.w*b0.w
            + a1.x*b1.x + a1.y*b1.y + a1.z*b1.z + a1.w*b1.w
            + a2.x*b2.x + a2.y*b2.y + a2.z*b2.z + a2.w*b2.w
            + a3.x*b3.x + a3.y*b3.y + a3.z*b3.z + a3.w*b3.w;
    tr += v * d; es += v;
    m[0]+=v*a0.x; m[1]+=v*a0.y; m[2]+=v*a0.z; m[3]+=v*a0.w;
    m[4]+=v*a1.x; m[5]+=v*a1.y; m[6]+=v*a1.z; m[7]+=v*a1.w;
    m[8]+=v*a2.x; m[9]+=v*a2.y; m[10]+=v*a2.z; m[11]+=v*a2.w;
    m[12]+=v*a3.x; m[13]+=v*a3.y; m[14]+=v*a3.z; m[15]+=v*a3.w;
  }
  #pragma unroll
  for (int off = 1; off < 64; off <<= 1) {
    tr += __shfl_xor(tr, off);
    es += __shfl_xor(es, off);
    #pragma unroll
    for (int i = 0; i < KC; ++i) m[i] += __shfl_xor(m[i], off);
  }
  if ((t & 63) == 0) {
    atomicAdd(&red[KC], tr);
    atomicAdd(&red[KC + 1], es);
    #pragma unroll
    for (int i = 0; i < KC; ++i) atomicAdd(&red[i], m[i]);
  }
  __syncthreads();
  if (t < KC)            atomicAdd(&ws[WS_M + t], red[t]);
  else if (t == KC)      atomicAdd(&ws[WS_TR], red[KC]);
  else if (t == KC + 1)  atomicAdd(&ws[WS_ESUM], red[KC + 1]);
}

// standalone finalize (fallback path only)
__global__ void finalize_kernel(float* __restrict__ ws,
                                float* __restrict__ out, int n) {
  finalize_body(ws, out, n);
}

extern "C" void kernel_launch(void* const* d_in, const int* in_sizes, int n_in,
                              void* d_out, int out_size, void* d_ws, size_t ws_size,
                              hipStream_t stream) {
  const float* F   = (const float*)d_in[0];
  const float* W   = (const float*)d_in[1];
  const float* b   = (const float*)d_in[2];
  const int* erow  = (const int*)d_in[3];
  const int* ecol  = (const int*)d_in[4];
  const float* evl = (const float*)d_in[5];
  const int n  = in_sizes[0] / DF;
  const int ne = in_sizes[3];
  float* out = (float*)d_out;
  float* S   = out + KC * DF;      // assignments live directly in d_out
  float* ws  = (float*)d_ws;

  const size_t shadow_bytes = (size_t)n * 16;   // fp8: 16 B/node
  const bool use_shadow = ws_size >= (size_t)SHDW_OFF_BYTES + shadow_bytes + 64;
  unsigned* Sh = use_shadow ? (unsigned*)((char*)d_ws + SHDW_OFF_BYTES) : nullptr;

  // zero accumulators + DONE counter via stream memset (one fewer dispatch)
  hipMemsetAsync(d_ws, 0, WS_TOTAL * sizeof(float), stream);

  assign_kernel<<<(n + 255) / 256, 256, 0, stream>>>(F, W, b, S, Sh, ws, n);

  const int pg = 2048;                          // pool blocks
  if (use_shadow) {
    const int eg = (ne + 2047) >> 11;           // edge blocks (2048 edges each)
    edge_pool_kernel<<<pg + eg, 256, 0, stream>>>(
        erow, ecol, evl, (const uint4*)Sh, F, S, ws, out, ne, n, pg, eg);
  } else {
    edge_kernel_f32<<<2048, 256, 0, stream>>>(erow, ecol, evl, S, ws, ne);
    edge_pool_kernel<<<pg, 256, 0, stream>>>(    // pure pool (eg = 0)
        erow, ecol, evl, (const uint4*)nullptr, F, S, ws, out, ne, n, pg, 0);
    finalize_kernel<<<1, 256, 0, stream>>>(ws, out, n);
  }
}

// Round 12
// 328.166 us; speedup vs baseline: 1.9753x; 1.9753x over previous
//
#include <hip/hip_runtime.h>
#include <math.h>

#define KC 16
#define DF 256

// ws layout
#define WS_POOLED 0          // [16*256] S^T F accumulator (floats)
#define WS_CS     4096       // [16] cluster sizes
#define WS_M      4112       // [16] m_k = sum_e val*S[row][k]
#define WS_TR     4128       // trace accumulator
#define WS_ESUM   4129       // sum of edge_val (= 2*n_edges)
#define WS_DONE   4130       // edge_pool completion counter (uint bits)
#define WS_TOTAL  4131
#define SHDW_OFF_BYTES 16640 // fp8 S shadow, 16 B/node, 16B-aligned

// NOTE: no __has_builtin / arch preprocessor gating (host/device pass divergence
// caused the round-0 core dump). gfx950 always has the fp8 cvt builtins.
// RULE (r10): W addresses must stay wave-uniform (scalar loads).
// RULE (r11): NO per-block __threadfence() — it compiles to an L2
// writeback/invalidate (per-XCD L2 coherence) and 3.6k of them thrash the
// cache (95->512 us). ws updates are global atomics (complete at the
// coherence point), so block completion only needs s_waitcnt vmcnt(0).

typedef float floatx2 __attribute__((ext_vector_type(2)));

// 16 fp8 (OCP e4m3fn) -> 16 f32 via 8 packed HW converts.
__device__ __forceinline__ void cvt16_fp8(uint4 u, float* f) {
  floatx2 p;
  p = __builtin_amdgcn_cvt_pk_f32_fp8(u.x, false); f[0] = p[0];  f[1] = p[1];
  p = __builtin_amdgcn_cvt_pk_f32_fp8(u.x, true);  f[2] = p[0];  f[3] = p[1];
  p = __builtin_amdgcn_cvt_pk_f32_fp8(u.y, false); f[4] = p[0];  f[5] = p[1];
  p = __builtin_amdgcn_cvt_pk_f32_fp8(u.y, true);  f[6] = p[0];  f[7] = p[1];
  p = __builtin_amdgcn_cvt_pk_f32_fp8(u.z, false); f[8] = p[0];  f[9] = p[1];
  p = __builtin_amdgcn_cvt_pk_f32_fp8(u.z, true);  f[10] = p[0]; f[11] = p[1];
  p = __builtin_amdgcn_cvt_pk_f32_fp8(u.w, false); f[12] = p[0]; f[13] = p[1];
  p = __builtin_amdgcn_cvt_pk_f32_fp8(u.w, true);  f[14] = p[0]; f[15] = p[1];
}

__device__ __forceinline__ void acc_edge1(uint4 A, uint4 B, float vq,
                                          float* m, float& tr, float& es) {
  float a[16], bb[16];
  cvt16_fp8(A, a); cvt16_fp8(B, bb);
  float d = 0.f;
  #pragma unroll
  for (int k = 0; k < 16; ++k) d += a[k] * bb[k];
  tr += vq * d; es += vq;
  #pragma unroll
  for (int k = 0; k < 16; ++k) m[k] += vq * a[k];
}

// ---------------------------------------------------------------------------
// assign: VERBATIM r4/r7 version (measured ~70 us): thread=node, W
// wave-uniform (scalar loads), F staged transposed in double-buffered LDS.
// ---------------------------------------------------------------------------
__global__ void __launch_bounds__(256, 2) assign_kernel(
    const float* __restrict__ F, const float* __restrict__ W,
    const float* __restrict__ b, float* __restrict__ S,
    unsigned* __restrict__ Sh, float* __restrict__ ws, int n) {
  __shared__ float Ft[2][32 * 257];
  __shared__ float cs_l[KC];
  const int t = threadIdx.x;
  if (t < KC) cs_l[t] = 0.0f;
  const int nb = blockIdx.x << 8;
  const int node = nb + t;
  const bool valid = node < n;
  const bool interior = (nb + 256 <= n);

  const int nl = t >> 3;          // staged node within tile (per 'it' offset)
  const int jc = t & 7;           // float4 slot within 32-feature row

  float4 pref[8];
  auto load_chunk = [&](int s) {
    #pragma unroll
    for (int it = 0; it < 8; ++it) {
      const int nn = nl + (it << 5);
      if (interior || nb + nn < n)
        pref[it] = *(const float4*)&F[(size_t)(nb + nn) * DF + (s << 5) + (jc << 2)];
      else
        pref[it] = make_float4(0.f, 0.f, 0.f, 0.f);
    }
  };

  float acc[KC];
  #pragma unroll
  for (int k = 0; k < KC; ++k) acc[k] = 0.f;

  load_chunk(0);
  for (int s = 0; s < 8; ++s) {
    float* __restrict__ B = Ft[s & 1];
    // Writes to buffer (s&1) are safe without a leading barrier: the last
    // reads of this buffer (compute s-2) precede the barrier of iter s-1.
    #pragma unroll
    for (int it = 0; it < 8; ++it) {
      const int nn = nl + (it << 5);
      const int d0 = jc << 2;
      B[(d0 + 0) * 257 + nn] = pref[it].x;
      B[(d0 + 1) * 257 + nn] = pref[it].y;
      B[(d0 + 2) * 257 + nn] = pref[it].z;
      B[(d0 + 3) * 257 + nn] = pref[it].w;
    }
    __syncthreads();
    if (s < 7) load_chunk(s + 1);  // in flight during compute below
    #pragma unroll
    for (int j = 0; j < 8; ++j) {
      const float fv0 = B[(4 * j + 0) * 257 + t];
      const float fv1 = B[(4 * j + 1) * 257 + t];
      const float fv2 = B[(4 * j + 2) * 257 + t];
      const float fv3 = B[(4 * j + 3) * 257 + t];
      const float* __restrict__ Wg = &W[(size_t)((s << 5) + (j << 2)) * KC];
      #pragma unroll
      for (int k = 0; k < KC; ++k)
        acc[k] += fv0 * Wg[k] + fv1 * Wg[KC + k]
                + fv2 * Wg[2 * KC + k] + fv3 * Wg[3 * KC + k];
    }
  }

  // thread-local softmax
  float mx = -1e30f;
  #pragma unroll
  for (int k = 0; k < KC; ++k) { acc[k] += b[k]; mx = fmaxf(mx, acc[k]); }
  float sum = 0.f;
  #pragma unroll
  for (int k = 0; k < KC; ++k) { acc[k] = __expf(acc[k] - mx); sum += acc[k]; }
  const float inv = 1.0f / sum;
  #pragma unroll
  for (int k = 0; k < KC; ++k) acc[k] *= inv;
  if (!valid) {
    #pragma unroll
    for (int k = 0; k < KC; ++k) acc[k] = 0.f;
  }
  if (valid) {
    float4* __restrict__ So = (float4*)&S[(size_t)node * KC];
    So[0] = make_float4(acc[0],  acc[1],  acc[2],  acc[3]);
    So[1] = make_float4(acc[4],  acc[5],  acc[6],  acc[7]);
    So[2] = make_float4(acc[8],  acc[9],  acc[10], acc[11]);
    So[3] = make_float4(acc[12], acc[13], acc[14], acc[15]);
    if (Sh) {
      unsigned w0, w1, w2, w3;
      w0 = __builtin_amdgcn_cvt_pk_fp8_f32(acc[0],  acc[1],  0,  false);
      w0 = __builtin_amdgcn_cvt_pk_fp8_f32(acc[2],  acc[3],  w0, true);
      w1 = __builtin_amdgcn_cvt_pk_fp8_f32(acc[4],  acc[5],  0,  false);
      w1 = __builtin_amdgcn_cvt_pk_fp8_f32(acc[6],  acc[7],  w1, true);
      w2 = __builtin_amdgcn_cvt_pk_fp8_f32(acc[8],  acc[9],  0,  false);
      w2 = __builtin_amdgcn_cvt_pk_fp8_f32(acc[10], acc[11], w2, true);
      w3 = __builtin_amdgcn_cvt_pk_fp8_f32(acc[12], acc[13], 0,  false);
      w3 = __builtin_amdgcn_cvt_pk_fp8_f32(acc[14], acc[15], w3, true);
      *(uint4*)&Sh[(size_t)node * 4] = make_uint4(w0, w1, w2, w3);
    }
  }
  // cluster sizes
  #pragma unroll
  for (int off = 1; off < 64; off <<= 1) {
    #pragma unroll
    for (int k = 0; k < KC; ++k) acc[k] += __shfl_xor(acc[k], off);
  }
  if ((t & 63) == 0) {
    #pragma unroll
    for (int k = 0; k < KC; ++k) atomicAdd(&cs_l[k], acc[k]);
  }
  __syncthreads();
  if (t < KC) atomicAdd(&ws[WS_CS + t], cs_l[t]);
}

// ---------------------------------------------------------------------------
// Edge body (fp8): contiguous 2048-edge chunk per block 'idx', all 16
// S-gathers into named registers before compute.
// ---------------------------------------------------------------------------
__device__ __forceinline__ void edge_body_fp8(
    const int* __restrict__ erow, const int* __restrict__ ecol,
    const float* __restrict__ evl, const uint4* __restrict__ S8,
    float* __restrict__ ws, int ne, int idx, float* __restrict__ red) {
  const int t = threadIdx.x;
  if (t < KC + 2) red[t] = 0.0f;
  __syncthreads();

  float m[KC];
  #pragma unroll
  for (int i = 0; i < KC; ++i) m[i] = 0.f;
  float tr = 0.f, es = 0.f;

  const int cbase = idx << 11;            // 2048 edges per block
  const int base = cbase + t;
  int r[8], c[8];
  float v[8];
  if (cbase + 2048 <= ne) {               // interior fast path
    #pragma unroll
    for (int i = 0; i < 8; ++i) {
      const int e = base + (i << 8);
      r[i] = erow[e]; c[i] = ecol[e]; v[i] = evl[e];
    }
  } else {
    #pragma unroll
    for (int i = 0; i < 8; ++i) {
      const int e = base + (i << 8);
      const bool ok = e < ne;
      r[i] = ok ? erow[e] : 0;
      c[i] = ok ? ecol[e] : 0;
      v[i] = ok ? evl[e] : 0.f;
    }
  }

  const uint4 A0 = S8[r[0]], B0 = S8[c[0]], A1 = S8[r[1]], B1 = S8[c[1]],
              A2 = S8[r[2]], B2 = S8[c[2]], A3 = S8[r[3]], B3 = S8[c[3]],
              A4 = S8[r[4]], B4 = S8[c[4]], A5 = S8[r[5]], B5 = S8[c[5]],
              A6 = S8[r[6]], B6 = S8[c[6]], A7 = S8[r[7]], B7 = S8[c[7]];
  acc_edge1(A0, B0, v[0], m, tr, es);
  acc_edge1(A1, B1, v[1], m, tr, es);
  acc_edge1(A2, B2, v[2], m, tr, es);
  acc_edge1(A3, B3, v[3], m, tr, es);
  acc_edge1(A4, B4, v[4], m, tr, es);
  acc_edge1(A5, B5, v[5], m, tr, es);
  acc_edge1(A6, B6, v[6], m, tr, es);
  acc_edge1(A7, B7, v[7], m, tr, es);

  #pragma unroll
  for (int off = 1; off < 64; off <<= 1) {
    tr += __shfl_xor(tr, off);
    es += __shfl_xor(es, off);
    #pragma unroll
    for (int i = 0; i < KC; ++i) m[i] += __shfl_xor(m[i], off);
  }
  if ((t & 63) == 0) {
    atomicAdd(&red[KC], tr);
    atomicAdd(&red[KC + 1], es);
    #pragma unroll
    for (int i = 0; i < KC; ++i) atomicAdd(&red[i], m[i]);
  }
  __syncthreads();
  if (t < KC)            atomicAdd(&ws[WS_M + t], red[t]);
  else if (t == KC)      atomicAdd(&ws[WS_TR], red[KC]);
  else if (t == KC + 1)  atomicAdd(&ws[WS_ESUM], red[KC + 1]);
}

// ---------------------------------------------------------------------------
// Pool body: r4 pool_kernel with explicit (idx, pg).
// ---------------------------------------------------------------------------
__device__ __forceinline__ void pool_body(
    const float* __restrict__ F, const float* __restrict__ S,
    float* __restrict__ ws, int n, int idx, int pg) {
  const int t = threadIdx.x;
  float acc[KC];
  #pragma unroll
  for (int i = 0; i < KC; ++i) acc[i] = 0.f;

  const int nch = n >> 5;
  for (int ch = idx; ch < nch; ch += pg) {
    const int base = ch << 5;
    float fl[32];
    #pragma unroll
    for (int i = 0; i < 32; ++i)
      fl[i] = F[(size_t)(base + i) * DF + t];
    #pragma unroll
    for (int i = 0; i < 32; ++i) {
      const float4* __restrict__ Sr = (const float4*)(S + (size_t)(base + i) * KC);
      const float4 s0 = Sr[0], s1 = Sr[1], s2 = Sr[2], s3 = Sr[3];
      const float f = fl[i];
      acc[0]+=f*s0.x;  acc[1]+=f*s0.y;  acc[2]+=f*s0.z;  acc[3]+=f*s0.w;
      acc[4]+=f*s1.x;  acc[5]+=f*s1.y;  acc[6]+=f*s1.z;  acc[7]+=f*s1.w;
      acc[8]+=f*s2.x;  acc[9]+=f*s2.y;  acc[10]+=f*s2.z; acc[11]+=f*s2.w;
      acc[12]+=f*s3.x; acc[13]+=f*s3.y; acc[14]+=f*s3.z; acc[15]+=f*s3.w;
    }
  }
  if (idx == 0) {                        // tail (n % 32)
    for (int i2 = nch << 5; i2 < n; ++i2) {
      const float f = F[(size_t)i2 * DF + t];
      const float* __restrict__ Sr = S + (size_t)i2 * KC;
      #pragma unroll
      for (int kk = 0; kk < KC; ++kk) acc[kk] += f * Sr[kk];
    }
  }
  const int rot = idx & 15;
  #pragma unroll
  for (int kk = 0; kk < KC; ++kk) {
    const int kidx = (kk + rot) & 15;
    atomicAdd(&ws[WS_POOLED + kidx * DF + t], acc[kidx]);
  }
}

// ---------------------------------------------------------------------------
// Finalize body: run by the LAST edge_pool block. All ws reads via
// atomicAdd(p, 0) -> coherence-point reads (no stale-L1 risk, no fence).
// ---------------------------------------------------------------------------
__device__ void finalize_body(float* __restrict__ ws, float* __restrict__ out,
                              int n) {
  __shared__ float s_cs[KC];
  const int t = threadIdx.x;
  if (t < KC) s_cs[t] = atomicAdd(&ws[WS_CS + t], 0.0f);
  __syncthreads();
  const float alpha = 1.6732632423543772f;
  const float scale = 1.0507009873554805f;
  for (int idx = t; idx < KC * DF; idx += 256) {
    const int k = idx >> 8;
    const float x = atomicAdd(&ws[WS_POOLED + idx], 0.0f) / s_cs[k];
    const float r = x > 0.f ? x : alpha * expm1f(x);
    out[idx] = scale * r;
  }
  if (t == 0) {
    const float esum = atomicAdd(&ws[WS_ESUM], 0.0f);   // = 2 * n_edges
    const float tr = atomicAdd(&ws[WS_TR], 0.0f);
    float sm2 = 0.f, sc2 = 0.f;
    for (int i = 0; i < KC; ++i) {
      const float mi = atomicAdd(&ws[WS_M + i], 0.0f);
      sm2 += mi * mi;
      const float ci = s_cs[i];
      sc2 += ci * ci;
    }
    const float spectral = -(tr - sm2 / esum) / esum;
    const float collapse = 0.1f * (sqrtf(sc2) / (float)n * 4.0f - 1.0f);
    const size_t off = (size_t)(KC * DF) + (size_t)n * KC;
    out[off] = spectral;
    out[off + 1] = collapse;
  }
}

// ---------------------------------------------------------------------------
// Merged edge+pool dispatch (r7: 95 us @ 1.2 TB/s) + last-block finalize.
// r12: block epilogue is s_waitcnt vmcnt(0) + done-counter — NOT
// __threadfence() (r11: per-block L2 writeback caused 95->512 us). All ws
// updates are device-scope atomics, complete at the coherence point once
// vmcnt retires, so no cache writeback is needed.
// ---------------------------------------------------------------------------
__global__ void __launch_bounds__(256) edge_pool_kernel(
    const int* __restrict__ erow, const int* __restrict__ ecol,
    const float* __restrict__ evl, const uint4* __restrict__ S8,
    const float* __restrict__ F, const float* __restrict__ S,
    float* __restrict__ ws, float* __restrict__ out,
    int ne, int n, int pg, int eg) {
  __shared__ float red[KC + 2];
  __shared__ int lastFlag;
  const int bid = blockIdx.x;
  const int mn = pg < eg ? pg : eg;
  const int nInter = 2 * mn;
  int role, idx;
  if (bid < nInter) { role = bid & 1; idx = bid >> 1; }
  else {
    const int rem = bid - nInter;
    role = (pg > eg) ? 0 : 1;
    idx = mn + rem;
  }
  if (role == 0) pool_body(F, S, ws, n, idx, pg);
  else           edge_body_fp8(erow, ecol, evl, S8, ws, ne, idx, red);

  // cheap completion: wait own vmem (atomics retire at coherence point),
  // block-sync, then one done-counter atomic. No L2 writeback.
  asm volatile("s_waitcnt vmcnt(0) lgkmcnt(0)" ::: "memory");
  __syncthreads();
  if (threadIdx.x == 0) {
    unsigned old = atomicAdd((unsigned*)ws + WS_DONE, 1u);
    lastFlag = (old == (unsigned)(gridDim.x - 1)) ? 1 : 0;
  }
  __syncthreads();
  if (lastFlag) finalize_body(ws, out, n);
}

// fp32 fallback (ws too small for the fp8 shadow) — runtime choice.
__global__ void __launch_bounds__(256) edge_kernel_f32(
    const int* __restrict__ erow, const int* __restrict__ ecol,
    const float* __restrict__ evl, const float* __restrict__ S,
    float* __restrict__ ws, int ne) {
  __shared__ float red[KC + 2];
  const int t = threadIdx.x;
  if (t < KC + 2) red[t] = 0.0f;
  __syncthreads();
  float m[KC];
  #pragma unroll
  for (int i = 0; i < KC; ++i) m[i] = 0.f;
  float tr = 0.f, es = 0.f;
  const int stride = gridDim.x * blockDim.x;
  for (int e = blockIdx.x * blockDim.x + t; e < ne; e += stride) {
    const int r = erow[e];
    const int c = ecol[e];
    const float v = evl[e];
    const float4* __restrict__ Sr = (const float4*)(S + (size_t)r * KC);
    const float4* __restrict__ Sc = (const float4*)(S + (size_t)c * KC);
    const float4 a0 = Sr[0], a1 = Sr[1], a2 = Sr[2], a3 = Sr[3];
    const float4 b0 = Sc[0], b1 = Sc[1], b2 = Sc[2], b3 = Sc[3];
    float d = a0.x*b0.x + a0.y*b0.y + a0.z*b0.z + a0.w*b0.w
            + a1.x*b1.x + a1.y*b1.y + a1.z*b1.z + a1.w*b1.w
            + a2.x*b2.x + a2.y*b2.y + a2.z*b2.z + a2.w*b2.w
            + a3.x*b3.x + a3.y*b3.y + a3.z*b3.z + a3.w*b3.w;
    tr += v * d; es += v;
    m[0]+=v*a0.x; m[1]+=v*a0.y; m[2]+=v*a0.z; m[3]+=v*a0.w;
    m[4]+=v*a1.x; m[5]+=v*a1.y; m[6]+=v*a1.z; m[7]+=v*a1.w;
    m[8]+=v*a2.x; m[9]+=v*a2.y; m[10]+=v*a2.z; m[11]+=v*a2.w;
    m[12]+=v*a3.x; m[13]+=v*a3.y; m[14]+=v*a3.z; m[15]+=v*a3.w;
  }
  #pragma unroll
  for (int off = 1; off < 64; off <<= 1) {
    tr += __shfl_xor(tr, off);
    es += __shfl_xor(es, off);
    #pragma unroll
    for (int i = 0; i < KC; ++i) m[i] += __shfl_xor(m[i], off);
  }
  if ((t & 63) == 0) {
    atomicAdd(&red[KC], tr);
    atomicAdd(&red[KC + 1], es);
    #pragma unroll
    for (int i = 0; i < KC; ++i) atomicAdd(&red[i], m[i]);
  }
  __syncthreads();
  if (t < KC)            atomicAdd(&ws[WS_M + t], red[t]);
  else if (t == KC)      atomicAdd(&ws[WS_TR], red[KC]);
  else if (t == KC + 1)  atomicAdd(&ws[WS_ESUM], red[KC + 1]);
}

extern "C" void kernel_launch(void* const* d_in, const int* in_sizes, int n_in,
                              void* d_out, int out_size, void* d_ws, size_t ws_size,
                              hipStream_t stream) {
  const float* F   = (const float*)d_in[0];
  const float* W   = (const float*)d_in[1];
  const float* b   = (const float*)d_in[2];
  const int* erow  = (const int*)d_in[3];
  const int* ecol  = (const int*)d_in[4];
  const float* evl = (const float*)d_in[5];
  const int n  = in_sizes[0] / DF;
  const int ne = in_sizes[3];
  float* out = (float*)d_out;
  float* S   = out + KC * DF;      // assignments live directly in d_out
  float* ws  = (float*)d_ws;

  const size_t shadow_bytes = (size_t)n * 16;   // fp8: 16 B/node
  const bool use_shadow = ws_size >= (size_t)SHDW_OFF_BYTES + shadow_bytes + 64;
  unsigned* Sh = use_shadow ? (unsigned*)((char*)d_ws + SHDW_OFF_BYTES) : nullptr;

  // zero accumulators + DONE counter via stream memset (one fewer dispatch)
  hipMemsetAsync(d_ws, 0, WS_TOTAL * sizeof(float), stream);

  assign_kernel<<<(n + 255) / 256, 256, 0, stream>>>(F, W, b, S, Sh, ws, n);

  const int pg = 2048;                          // pool blocks
  if (use_shadow) {
    const int eg = (ne + 2047) >> 11;           // edge blocks (2048 edges each)
    edge_pool_kernel<<<pg + eg, 256, 0, stream>>>(
        erow, ecol, evl, (const uint4*)Sh, F, S, ws, out, ne, n, pg, eg);
  } else {
    edge_kernel_f32<<<2048, 256, 0, stream>>>(erow, ecol, evl, S, ws, ne);
    edge_pool_kernel<<<pg, 256, 0, stream>>>(    // pure pool (eg = 0)
        erow, ecol, evl, (const uint4*)nullptr, F, S, ws, out, ne, n, pg, 0);
  }
}